// Round 7
// baseline (289.092 us; speedup 1.0000x reference)
//
#include <hip/hip_runtime.h>
#include <hip/hip_cooperative_groups.h>
#include <hip/hip_bf16.h>
#include <math.h>
#include <stdint.h>
#include <limits.h>

namespace cg = cooperative_groups;

#define BB 8
#define NC 4
#define HH 192
#define WW 192
#define HWP (HH * WW)
#define NPAIR 24            // B * (NC-1)
#define NPD 48              // NPAIR * 2 fields
#define NWRD 576            // HH rows * 3 u64 words per field (= words per image)
#define NCHUNK 16
#define WPC (NWRD / NCHUNK) // 36 words per chunk
#define GB 768              // grid blocks (= NCHUNK * NPD); 3 blocks/CU co-resident
#define PCAP 12288          // pick-phase LDS value capacity (n~9.2k typical)
#define BIGI 1000000000     // matches reference BIG = 1e9 (exact in int32 and f32)

typedef unsigned long long u64;

struct P2 {                 // query phase (18.6 KB)
    u64 sF[NWRD];           // fg of pd
    u64 sG[NWRD];           // fg of pd^1
    u64 sS[NWRD];           // surface of pd (field searched)
    uint16_t qb[WPC * 64];  // queries of this chunk (<=2304)
    int wcnt[WPC + 1];
    int sbase;
};
struct P3 {                 // pick phase (49.2 KB)
    int vals[PCAP];
    int sw[4];
};
union ShU { P2 p2; P3 p3; };

// surface word (row i, word k) from fg bitmap F (borders = background)
__device__ __forceinline__ u64 surf_word(const u64* F, int i, int k) {
    u64 r0 = F[i * 3], r1 = F[i * 3 + 1], r2 = F[i * 3 + 2];
    u64 r = F[i * 3 + k];
    u64 u = (i > 0) ? F[(i - 1) * 3 + k] : 0ull;
    u64 d = (i < HH - 1) ? F[(i + 1) * 3 + k] : 0ull;
    u64 lf, rt;
    if (k == 0)      { lf = r0 << 1;                rt = (r0 >> 1) | (r1 << 63); }
    else if (k == 1) { lf = (r1 << 1) | (r0 >> 63); rt = (r1 >> 1) | (r2 << 63); }
    else             { lf = (r2 << 1) | (r1 >> 63); rt = r2 >> 1; }
    return r & ~(u & d & lf & rt);
}

// nearest set-bit horizontal distance to column j in 192-bit row; INT_MAX if empty
__device__ __forceinline__ int rowdist(const u64* w, int j) {
    int qw = j >> 6, qb2 = j & 63;
    int dr = INT_MAX, dl = INT_MAX;
    u64 m = w[qw] & (~0ull << qb2);
    if (m) dr = ((qw << 6) + __ffsll(m) - 1) - j;
    else {
        for (int k = qw + 1; k < 3; ++k)
            if (w[k]) { dr = ((k << 6) + __ffsll(w[k]) - 1) - j; break; }
    }
    u64 ml = w[qw] & (~0ull >> (63 - qb2));
    if (ml) dl = j - ((qw << 6) + 63 - __clzll((long long)ml));
    else {
        for (int k = qw - 1; k >= 0; --k)
            if (w[k]) { dl = j - ((k << 6) + 63 - __clzll((long long)w[k])); break; }
    }
    return min(dl, dr);
}

// prep one 64-pixel word: argmax over classes + ballot-packed fg bits
__device__ __forceinline__ void prep_word(int w, int lane, const float* __restrict__ logits,
                                          const int* __restrict__ target, u64* __restrict__ fgbits) {
    int b = w / NWRD;                // words per image = NWRD
    int g = w - b * NWRD;
    int p = (g << 6) + lane;
    const float* base = logits + (size_t)b * NC * HWP + p;
    float l0 = base[0], l1 = base[HWP], l2 = base[2 * HWP], l3 = base[3 * HWP];
    int pred = 0; float best = l0;
    if (l1 > best) { best = l1; pred = 1; }   // strict > keeps first max (jnp.argmax)
    if (l2 > best) { best = l2; pred = 2; }
    if (l3 > best) { best = l3; pred = 3; }
    int t = target[(size_t)b * HWP + p];
#pragma unroll
    for (int cls = 1; cls <= 3; ++cls) {
        u64 mp = __ballot(pred == cls);
        u64 mt = __ballot(t == cls);
        if (lane == 0) {
            int pair = b * 3 + (cls - 1);
            fgbits[(size_t)(pair * 2 + 0) * NWRD + g] = mp;
            fgbits[(size_t)(pair * 2 + 1) * NWRD + g] = mt;
        }
    }
}

__device__ __forceinline__ int block_reduce_add(int v, int* sw, int tid) {
    for (int off = 32; off; off >>= 1) v += __shfl_down(v, off);
    if ((tid & 63) == 0) sw[tid >> 6] = v;
    __syncthreads();
    int r = sw[0] + sw[1] + sw[2] + sw[3];
    __syncthreads();
    return r;
}
__device__ __forceinline__ int block_reduce_max(int v, int* sw, int tid) {
    for (int off = 32; off; off >>= 1) v = max(v, __shfl_down(v, off));
    if ((tid & 63) == 0) sw[tid >> 6] = v;
    __syncthreads();
    int r = max(max(sw[0], sw[1]), max(sw[2], sw[3]));
    __syncthreads();
    return r;
}

// ---- the whole metric in one cooperative kernel -----------------------------
__global__ __launch_bounds__(256, 3) void k_all(const float* __restrict__ logits,
                        const int* __restrict__ target, u64* __restrict__ fgbits,
                        int* __restrict__ list, int* __restrict__ cnt,
                        float* __restrict__ res, float* __restrict__ out) {
    cg::grid_group grid = cg::this_grid();
    __shared__ ShU sh;
    int tid = threadIdx.x, bid = blockIdx.x;

    // ---- phase 0+1: zero cnt; argmax + bit-pack fg masks ----
    if (bid == 0 && tid < NPD) cnt[tid] = 0;
    {
        int gtid = bid * 256 + tid;
        int w0 = gtid >> 6, lane = gtid & 63;            // waves 0..3071, words 0..4607
        prep_word(w0, lane, logits, target, fgbits);
        int w1 = w0 + 3072;
        if (w1 < BB * NWRD) prep_word(w1, lane, logits, target, fgbits);  // wave-uniform
    }
    grid.sync();

    // ---- phase 2: surface bits + query enumeration + exact 2D nearest search ----
    {
        int pd = bid >> 4, chunk = bid & 15, qpd = pd ^ 1;
        for (int t = tid; t < NWRD; t += 256) {
            sh.p2.sF[t] = fgbits[(size_t)pd * NWRD + t];
            sh.p2.sG[t] = fgbits[(size_t)qpd * NWRD + t];
        }
        __syncthreads();
        for (int w = tid; w < NWRD; w += 256) sh.p2.sS[w] = surf_word(sh.p2.sF, w / 3, w % 3);

        u64 myq = 0;
        if (tid < WPC) {
            int w = chunk * WPC + tid;
            myq = surf_word(sh.p2.sG, w / 3, w % 3);
            sh.p2.wcnt[tid] = __popcll(myq);
        }
        __syncthreads();
        if (tid == 0) {
            int acc = 0;
            for (int w = 0; w < WPC; ++w) { int c = sh.p2.wcnt[w]; sh.p2.wcnt[w] = acc; acc += c; }
            sh.p2.wcnt[WPC] = acc;
            sh.p2.sbase = atomicAdd(&cnt[pd], acc);
        }
        __syncthreads();
        if (tid < WPC) {
            int w = chunk * WPC + tid;
            int i = w / 3, k = w % 3;
            int off = sh.p2.wcnt[tid];
            u64 m = myq;
            while (m) { int bi = __ffsll(m) - 1; m &= m - 1; sh.p2.qb[off++] = (uint16_t)((i << 8) | (k * 64 + bi)); }
        }
        __syncthreads();

        int nq = sh.p2.wcnt[WPC], base = sh.p2.sbase;
        for (int q = tid; q < nq; q += 256) {
            int e = sh.p2.qb[q];
            int qi = e >> 8, qj = e & 255;
            int best = BIGI;
            for (int s = 0; s < HH; ++s) {
                if (s * s >= best) break;                  // exact prune
                int r = qi - s;
                if (r >= 0) {
                    int dj = rowdist(sh.p2.sS + r * 3, qj);
                    if (dj != INT_MAX) best = min(best, s * s + dj * dj);
                }
                r = qi + s;
                if (s > 0 && r < HH) {
                    int dj = rowdist(sh.p2.sS + r * 3, qj);
                    if (dj != INT_MAX) best = min(best, s * s + dj * dj);
                }
            }
            list[(size_t)pd * HWP + base + q] = best;
        }
    }
    grid.sync();

    // ---- phase 3: exact max + k-th smallest per pd (blocks 0..47) ----
    if (bid < NPD) {
        int pd = bid;
        int n = cnt[pd];
        const int* L = list + (size_t)pd * HWP;
        int m = min(n, PCAP);
        for (int k = tid; k < m; k += 256) sh.p3.vals[k] = L[k];
        __syncthreads();

        int lmax = -1;
        for (int k = tid; k < m; k += 256) lmax = max(lmax, sh.p3.vals[k]);
        for (int k = PCAP + tid; k < n; k += 256) lmax = max(lmax, L[k]);   // overflow
        int vmax = block_reduce_max(lmax, sh.p3.sw, tid);

        if (n == 0) {
            if (tid == 0) { res[pd * 2 + 0] = INFINITY; res[pd * 2 + 1] = INFINITY; }
        } else {
            // replicate jnp: idx = clip(ceil(f32(0.95)*f32(n)) - 1, 0, ...); k = idx+1
            int kk;
            { float kf = ceilf(0.95f * (float)n); kk = (int)kf; if (kk < 1) kk = 1; if (kk > n) kk = n; }
            // binary search: smallest v in [0, min(vmax,72962)] with count(<=v) >= kk
            int lo = 0, hi = min(vmax, 72962);
            while (lo < hi) {
                int mid = (lo + hi) >> 1;
                int c = 0;
                for (int k = tid; k < m; k += 256) if (sh.p3.vals[k] <= mid) c++;
                for (int k = PCAP + tid; k < n; k += 256) if (L[k] <= mid) c++;
                int tot = block_reduce_add(c, sh.p3.sw, tid);
                if (tot >= kk) hi = mid; else lo = mid + 1;
            }
            int c = 0;
            for (int k = tid; k < m; k += 256) if (sh.p3.vals[k] <= lo) c++;
            for (int k = PCAP + tid; k < n; k += 256) if (L[k] <= lo) c++;
            int tot = block_reduce_add(c, sh.p3.sw, tid);
            if (tid == 0) {
                int v95 = (tot >= kk) ? lo : BIGI;   // not enough reals -> BIGI (all-BIG case)
                res[pd * 2 + 0] = sqrtf((float)vmax);
                res[pd * 2 + 1] = sqrtf((float)v95);
            }
        }
    }
    grid.sync();

    // ---- phase 4: robust max across directions, mean over pairs (block 0) ----
    if (bid == 0 && tid < 64) {
        float v100 = 0.0f, v95 = 0.0f;
        if (tid < NPAIR) {
            v100 = fmaxf(res[tid * 4 + 0], res[tid * 4 + 2]);
            v95  = fmaxf(res[tid * 4 + 1], res[tid * 4 + 3]);
        }
        for (int off = 32; off; off >>= 1) {
            v100 += __shfl_down(v100, off);
            v95  += __shfl_down(v95, off);
        }
        if (tid == 0) {
            out[0] = v100 / (float)NPAIR;
            out[1] = v95 / (float)NPAIR;
        }
    }
}

extern "C" void kernel_launch(void* const* d_in, const int* in_sizes, int n_in,
                              void* d_out, int out_size, void* d_ws, size_t ws_size,
                              hipStream_t stream) {
    const float* logits = (const float*)d_in[0];
    const int* target = (const int*)d_in[1];
    float* out = (float*)d_out;

    uint8_t* ws = (uint8_t*)d_ws;
    u64*   fgbits = (u64*)ws;                    // 48*576*8 = 221184 B
    int*   list   = (int*)(ws + 221184);         // 48*HWP*4 = 7077888 B
    int*   cnt    = (int*)(ws + 7299072);        // 48 ints
    float* res    = (float*)(ws + 7299264);      // 96 floats

    void* args[] = { (void*)&logits, (void*)&target, (void*)&fgbits, (void*)&list,
                     (void*)&cnt, (void*)&res, (void*)&out };
    hipLaunchCooperativeKernel((void*)k_all, dim3(GB), dim3(256), args, 0, stream);
}

// Round 8
// 95.846 us; speedup vs baseline: 3.0162x; 3.0162x over previous
//
#include <hip/hip_runtime.h>
#include <hip/hip_bf16.h>
#include <math.h>
#include <stdint.h>
#include <limits.h>

#define BB 8
#define NC 4
#define HH 192
#define WW 192
#define HWP (HH * WW)
#define NPAIR 24            // B * (NC-1)
#define NPD 48              // NPAIR * 2 fields
#define NWRD 576            // HH rows * 3 u64 words per field (= words per image)
#define NCHUNK 16
#define WPC (NWRD / NCHUNK) // 36 words per chunk
#define PCAP 12288          // pick-phase LDS value capacity (n~9.2k typical)
#define BIGI 1000000000     // matches reference BIG = 1e9 (exact in int32 and f32)

typedef unsigned long long u64;

// ---- kernel 1: argmax + bit-packed fg masks; block 0 zeroes cnt/ticket ------
// wave = 64 consecutive pixels -> __ballot builds one u64 mask word directly.
__global__ void k_prep(const float* __restrict__ logits, const int* __restrict__ target,
                       u64* __restrict__ fgbits, int* __restrict__ cnt) {
    if (blockIdx.x == 0 && threadIdx.x < NPD + 1) cnt[threadIdx.x] = 0;  // cnt[48]=ticket
    int idx = blockIdx.x * 256 + threadIdx.x;
    int b = idx / HWP;
    int p = idx - b * HWP;
    const float* base = logits + (size_t)b * NC * HWP + p;
    float l0 = base[0], l1 = base[HWP], l2 = base[2 * HWP], l3 = base[3 * HWP];
    int pred = 0; float best = l0;
    if (l1 > best) { best = l1; pred = 1; }   // strict > keeps first max (jnp.argmax)
    if (l2 > best) { best = l2; pred = 2; }
    if (l3 > best) { best = l3; pred = 3; }
    int t = target[(size_t)b * HWP + p];
    int lane = threadIdx.x & 63;
    int g = p >> 6;   // word index within field; bit = col&63 (word = i*3 + (j>>6))
#pragma unroll
    for (int cls = 1; cls <= 3; ++cls) {
        u64 mp = __ballot(pred == cls);
        u64 mt = __ballot(t == cls);
        if (lane == 0) {
            int pair = b * 3 + (cls - 1);
            fgbits[(size_t)(pair * 2 + 0) * NWRD + g] = mp;
            fgbits[(size_t)(pair * 2 + 1) * NWRD + g] = mt;
        }
    }
}

// surface word (row i, word k) from fg bitmap F (borders = background)
__device__ __forceinline__ u64 surf_word(const u64* F, int i, int k) {
    u64 r0 = F[i * 3], r1 = F[i * 3 + 1], r2 = F[i * 3 + 2];
    u64 r = F[i * 3 + k];
    u64 u = (i > 0) ? F[(i - 1) * 3 + k] : 0ull;
    u64 d = (i < HH - 1) ? F[(i + 1) * 3 + k] : 0ull;
    u64 lf, rt;
    if (k == 0)      { lf = r0 << 1;                rt = (r0 >> 1) | (r1 << 63); }
    else if (k == 1) { lf = (r1 << 1) | (r0 >> 63); rt = (r1 >> 1) | (r2 << 63); }
    else             { lf = (r2 << 1) | (r1 >> 63); rt = r2 >> 1; }
    return r & ~(u & d & lf & rt);
}

// nearest set-bit horizontal distance to column j in 192-bit row; INT_MAX if empty
__device__ __forceinline__ int rowdist(const u64* w, int j) {
    int qw = j >> 6, qb2 = j & 63;
    int dr = INT_MAX, dl = INT_MAX;
    u64 m = w[qw] & (~0ull << qb2);
    if (m) dr = ((qw << 6) + __ffsll(m) - 1) - j;
    else {
        for (int k = qw + 1; k < 3; ++k)
            if (w[k]) { dr = ((k << 6) + __ffsll(w[k]) - 1) - j; break; }
    }
    u64 ml = w[qw] & (~0ull >> (63 - qb2));
    if (ml) dl = j - ((qw << 6) + 63 - __clzll((long long)ml));
    else {
        for (int k = qw - 1; k >= 0; --k)
            if (w[k]) { dl = j - ((k << 6) + 63 - __clzll((long long)w[k])); break; }
    }
    return min(dl, dr);
}

// ---- kernel 2: surface bits + query enumeration + exact 2D nearest search ---
// Block (chunk, pd): field = surface of pd; queries = surface pixels of pd^1 in
// word slice [chunk*WPC, ...). Empty field -> BIGI exactly (reference BIG path).
// grid: (NCHUNK, NPD), block: 256
__global__ __launch_bounds__(256) void k_query(const u64* __restrict__ fgbits,
                        int* __restrict__ list, int* __restrict__ cnt) {
    int chunk = blockIdx.x, pd = blockIdx.y, qpd = pd ^ 1;
    int tid = threadIdx.x;
    __shared__ u64 sF[NWRD];               // fg of pd
    __shared__ u64 sG[NWRD];               // fg of pd^1
    __shared__ u64 sS[NWRD];               // surface of pd (field searched)
    __shared__ uint16_t qb[WPC * 64];      // queries of this chunk (<=2304)
    __shared__ int wcnt[WPC + 1];
    __shared__ int sbase;

    for (int t = tid; t < NWRD; t += 256) {
        sF[t] = fgbits[(size_t)pd * NWRD + t];
        sG[t] = fgbits[(size_t)qpd * NWRD + t];
    }
    __syncthreads();
    for (int w = tid; w < NWRD; w += 256) sS[w] = surf_word(sF, w / 3, w % 3);

    u64 myq = 0;
    if (tid < WPC) {
        int w = chunk * WPC + tid;
        myq = surf_word(sG, w / 3, w % 3);
        wcnt[tid] = __popcll(myq);
    }
    __syncthreads();
    if (tid == 0) {
        int acc = 0;
        for (int w = 0; w < WPC; ++w) { int c = wcnt[w]; wcnt[w] = acc; acc += c; }
        wcnt[WPC] = acc;
        sbase = atomicAdd(&cnt[pd], acc);
    }
    __syncthreads();
    if (tid < WPC) {
        int w = chunk * WPC + tid;
        int i = w / 3, k = w % 3;
        int off = wcnt[tid];
        u64 m = myq;
        while (m) { int bi = __ffsll(m) - 1; m &= m - 1; qb[off++] = (uint16_t)((i << 8) | (k * 64 + bi)); }
    }
    __syncthreads();

    int nq = wcnt[WPC], base = sbase;
    for (int q = tid; q < nq; q += 256) {
        int e = qb[q];
        int qi = e >> 8, qj = e & 255;
        int best = BIGI;
        for (int s = 0; s < HH; ++s) {
            if (s * s >= best) break;                      // exact prune
            int r = qi - s;
            if (r >= 0) {
                int dj = rowdist(sS + r * 3, qj);
                if (dj != INT_MAX) best = min(best, s * s + dj * dj);
            }
            r = qi + s;
            if (s > 0 && r < HH) {
                int dj = rowdist(sS + r * 3, qj);
                if (dj != INT_MAX) best = min(best, s * s + dj * dj);
            }
        }
        list[(size_t)pd * HWP + base + q] = best;
    }
}

// ---- kernel 3: pick per pd + last-block final reduction ---------------------
// grid: NPD, block: 1024. No atomic-histograms (contention) — binary search on
// value with block-reduced counts; then ticket: last finished block means all
// res[] written -> reduce 24-pair mean.
__global__ __launch_bounds__(1024) void k_pickfinal(const int* __restrict__ list,
                        int* __restrict__ cnt, float* __restrict__ res,
                        float* __restrict__ out) {
    int pd = blockIdx.x, tid = threadIdx.x;
    int n = cnt[pd];
    const int* L = list + (size_t)pd * HWP;
    __shared__ int vals[PCAP];
    __shared__ int sw[16];
    __shared__ int stot;
    __shared__ int slast;

    int m = min(n, PCAP);
    for (int k = tid; k < m; k += 1024) vals[k] = L[k];
    __syncthreads();

    int lmax = -1;
    for (int k = tid; k < m; k += 1024) lmax = max(lmax, vals[k]);
    for (int k = PCAP + tid; k < n; k += 1024) lmax = max(lmax, L[k]);   // overflow
    for (int off = 32; off; off >>= 1) lmax = max(lmax, __shfl_down(lmax, off));
    if ((tid & 63) == 0) sw[tid >> 6] = lmax;
    __syncthreads();
    if (tid == 0) { int v = -1; for (int w = 0; w < 16; ++w) v = max(v, sw[w]); stot = v; }
    __syncthreads();
    int vmax = stot;
    __syncthreads();

    if (n == 0) {
        if (tid == 0) { res[pd * 2 + 0] = INFINITY; res[pd * 2 + 1] = INFINITY; }
    } else {
        // replicate jnp: idx = clip(ceil(f32(0.95)*f32(n)) - 1, 0, ...); k = idx+1
        int kk;
        { float kf = ceilf(0.95f * (float)n); kk = (int)kf; if (kk < 1) kk = 1; if (kk > n) kk = n; }
        // binary search: smallest v in [0, min(vmax,72962)] with count(<=v) >= kk
        int lo = 0, hi = min(vmax, 72962);
        while (lo < hi) {
            int mid = (lo + hi) >> 1;
            int c = 0;
            for (int k = tid; k < m; k += 1024) if (vals[k] <= mid) c++;
            for (int k = PCAP + tid; k < n; k += 1024) if (L[k] <= mid) c++;
            for (int off = 32; off; off >>= 1) c += __shfl_down(c, off);
            if ((tid & 63) == 0) sw[tid >> 6] = c;
            __syncthreads();
            if (tid == 0) { int s = 0; for (int w = 0; w < 16; ++w) s += sw[w]; stot = s; }
            __syncthreads();
            if (stot >= kk) hi = mid; else lo = mid + 1;
            __syncthreads();
        }
        int c = 0;
        for (int k = tid; k < m; k += 1024) if (vals[k] <= lo) c++;
        for (int k = PCAP + tid; k < n; k += 1024) if (L[k] <= lo) c++;
        for (int off = 32; off; off >>= 1) c += __shfl_down(c, off);
        if ((tid & 63) == 0) sw[tid >> 6] = c;
        __syncthreads();
        if (tid == 0) {
            int s = 0; for (int w = 0; w < 16; ++w) s += sw[w];
            int v95 = (s >= kk) ? lo : BIGI;   // not enough reals -> BIGI (all-BIG case)
            res[pd * 2 + 0] = sqrtf((float)vmax);
            res[pd * 2 + 1] = sqrtf((float)v95);
        }
    }

    // ---- last-block-done final reduction (ticket at cnt[NPD]) ----
    __threadfence();                      // make res[pd] visible device-wide
    if (tid == 0) slast = atomicAdd(&cnt[NPD], 1);
    __syncthreads();
    if (slast == NPD - 1 && tid < 64) {
        __threadfence();                  // acquire: see all other blocks' res
        volatile float* vres = (volatile float*)res;
        float v100 = 0.0f, v95 = 0.0f;
        if (tid < NPAIR) {
            float a0 = vres[tid * 4 + 0], a2 = vres[tid * 4 + 2];
            float a1 = vres[tid * 4 + 1], a3 = vres[tid * 4 + 3];
            v100 = fmaxf(a0, a2);
            v95  = fmaxf(a1, a3);
        }
        for (int off = 32; off; off >>= 1) {
            v100 += __shfl_down(v100, off);
            v95  += __shfl_down(v95, off);
        }
        if (tid == 0) {
            out[0] = v100 / (float)NPAIR;
            out[1] = v95 / (float)NPAIR;
        }
    }
}

extern "C" void kernel_launch(void* const* d_in, const int* in_sizes, int n_in,
                              void* d_out, int out_size, void* d_ws, size_t ws_size,
                              hipStream_t stream) {
    const float* logits = (const float*)d_in[0];
    const int* target = (const int*)d_in[1];
    float* out = (float*)d_out;

    uint8_t* ws = (uint8_t*)d_ws;
    u64*   fgbits = (u64*)ws;                    // 48*576*8 = 221184 B
    int*   list   = (int*)(ws + 221184);         // 48*HWP*4 = 7077888 B
    int*   cnt    = (int*)(ws + 7299072);        // 48 ints + 1 ticket
    float* res    = (float*)(ws + 7299328);      // 96 floats

    k_prep<<<(BB * HWP) / 256, 256, 0, stream>>>(logits, target, fgbits, cnt);
    k_query<<<dim3(NCHUNK, NPD), 256, 0, stream>>>(fgbits, list, cnt);
    k_pickfinal<<<NPD, 1024, 0, stream>>>(list, cnt, res, out);
}

// Round 9
// 90.022 us; speedup vs baseline: 3.2113x; 1.0647x over previous
//
#include <hip/hip_runtime.h>
#include <hip/hip_bf16.h>
#include <math.h>
#include <stdint.h>
#include <limits.h>

#define BB 8
#define NC 4
#define HH 192
#define WW 192
#define HWP (HH * WW)
#define NPAIR 24            // B * (NC-1)
#define NPD 48              // NPAIR * 2 fields
#define NWRD 576            // HH rows * 3 u64 words per field (= words per image)
#define PCAP 16384          // LDS query capacity (bench n ~ 9.2k); spill path beyond
#define BIGI 1000000000     // matches reference BIG = 1e9 (exact in int32 and f32)

typedef unsigned long long u64;

// ---- kernel 1: argmax + bit-packed fg masks for all 48 (pair,type) fields ---
// wave = 64 consecutive pixels -> __ballot builds one u64 mask word directly.
__global__ void k_prep(const float* __restrict__ logits, const int* __restrict__ target,
                       u64* __restrict__ fgbits) {
    int idx = blockIdx.x * 256 + threadIdx.x;
    int b = idx / HWP;
    int p = idx - b * HWP;
    const float* base = logits + (size_t)b * NC * HWP + p;
    float l0 = base[0], l1 = base[HWP], l2 = base[2 * HWP], l3 = base[3 * HWP];
    int pred = 0; float best = l0;
    if (l1 > best) { best = l1; pred = 1; }   // strict > keeps first max (jnp.argmax)
    if (l2 > best) { best = l2; pred = 2; }
    if (l3 > best) { best = l3; pred = 3; }
    int t = target[(size_t)b * HWP + p];
    int lane = threadIdx.x & 63;
    int g = p >> 6;   // word index within field; bit = col&63 (word = i*3 + (j>>6))
#pragma unroll
    for (int cls = 1; cls <= 3; ++cls) {
        u64 mp = __ballot(pred == cls);
        u64 mt = __ballot(t == cls);
        if (lane == 0) {
            int pair = b * 3 + (cls - 1);
            fgbits[(size_t)(pair * 2 + 0) * NWRD + g] = mp;
            fgbits[(size_t)(pair * 2 + 1) * NWRD + g] = mt;
        }
    }
}

// surface word (row i, word k) from fg bitmap F (borders = background)
__device__ __forceinline__ u64 surf_word(const u64* F, int i, int k) {
    u64 r0 = F[i * 3], r1 = F[i * 3 + 1], r2 = F[i * 3 + 2];
    u64 r = F[i * 3 + k];
    u64 u = (i > 0) ? F[(i - 1) * 3 + k] : 0ull;
    u64 d = (i < HH - 1) ? F[(i + 1) * 3 + k] : 0ull;
    u64 lf, rt;
    if (k == 0)      { lf = r0 << 1;                rt = (r0 >> 1) | (r1 << 63); }
    else if (k == 1) { lf = (r1 << 1) | (r0 >> 63); rt = (r1 >> 1) | (r2 << 63); }
    else             { lf = (r2 << 1) | (r1 >> 63); rt = r2 >> 1; }
    return r & ~(u & d & lf & rt);
}

// nearest set-bit horizontal distance to column j in 192-bit row; INT_MAX if empty
__device__ __forceinline__ int rowdist(const u64* w, int j) {
    int qw = j >> 6, qb2 = j & 63;
    int dr = INT_MAX, dl = INT_MAX;
    u64 m = w[qw] & (~0ull << qb2);
    if (m) dr = ((qw << 6) + __ffsll(m) - 1) - j;
    else {
        for (int k = qw + 1; k < 3; ++k)
            if (w[k]) { dr = ((k << 6) + __ffsll(w[k]) - 1) - j; break; }
    }
    u64 ml = w[qw] & (~0ull >> (63 - qb2));
    if (ml) dl = j - ((qw << 6) + 63 - __clzll((long long)ml));
    else {
        for (int k = qw - 1; k >= 0; --k)
            if (w[k]) { dl = j - ((k << 6) + 63 - __clzll((long long)w[k])); break; }
    }
    return min(dl, dr);
}

// exact nearest-surface d^2 from (qi,qj): outward row rings, prune s^2 >= best.
// Empty field -> BIGI exactly (reference BIG-penalty path).
__device__ __forceinline__ int nearest2(const u64* sS, int qi, int qj) {
    int best = BIGI;
    for (int s = 0; s < HH; ++s) {
        if (s * s >= best) break;
        int r = qi - s;
        if (r >= 0) {
            int dj = rowdist(sS + r * 3, qj);
            if (dj != INT_MAX) best = min(best, s * s + dj * dj);
        }
        r = qi + s;
        if (s > 0 && r < HH) {
            int dj = rowdist(sS + r * 3, qj);
            if (dj != INT_MAX) best = min(best, s * s + dj * dj);
        }
    }
    return best;
}

// ---- kernel 2: per-pd fused query + percentile pick (no global round-trip) --
// Block pd: field = surface of pd; queries = surface pixels of pd^1.
// Coords via prefix-sum enumeration into LDS qb; distances into registers
// (k = tid + t*1024); exact k-th smallest via binary search on value with
// block-reduced counts. Spill to global only if n > PCAP (not hit in bench).
// grid: NPD, block: 1024
__global__ __launch_bounds__(1024) void k_main(const u64* __restrict__ fgbits,
                        uint16_t* __restrict__ spillq, int* __restrict__ spillv,
                        float* __restrict__ res) {
    int pd = blockIdx.x, qpd = pd ^ 1;
    int tid = threadIdx.x, lane = tid & 63, wid = tid >> 6;
    __shared__ u64 sF[NWRD];           // fg of pd
    __shared__ u64 sG[NWRD];           // fg of pd^1
    __shared__ u64 sS[NWRD];           // surface of pd (field searched)
    __shared__ uint16_t qb[PCAP];      // query coords (i<<8 | j)
    __shared__ int swt[16], swo[16];
    __shared__ int sn, stot, sw[16];

    if (tid < NWRD) {
        sF[tid] = fgbits[(size_t)pd * NWRD + tid];
        sG[tid] = fgbits[(size_t)qpd * NWRD + tid];
    }
    __syncthreads();

    u64 myq = 0; int c = 0;
    if (tid < NWRD) {
        sS[tid] = surf_word(sF, tid / 3, tid % 3);
        myq = surf_word(sG, tid / 3, tid % 3);
        c = __popcll(myq);
    }
    // block prefix-sum of per-word query counts (wave scan + wave totals)
    int inc = c;
    for (int off = 1; off < 64; off <<= 1) { int t = __shfl_up(inc, off); if (lane >= off) inc += t; }
    if (lane == 63) swt[wid] = inc;
    __syncthreads();
    if (tid == 0) {
        int acc = 0;
        for (int w = 0; w < 16; ++w) { swo[w] = acc; acc += swt[w]; }
        sn = acc;
    }
    __syncthreads();   // sS complete + offsets ready
    int n = sn;

    // emit coords at exclusive offset
    if (c > 0) {
        int off = swo[wid] + inc - c;
        int i = tid / 3, k = tid % 3;
        u64 m = myq;
        while (m) {
            int bi = __ffsll(m) - 1; m &= m - 1;
            uint16_t coord = (uint16_t)((i << 8) | (k * 64 + bi));
            if (off < PCAP) qb[off] = coord;
            else spillq[(size_t)pd * HWP + off - PCAP] = coord;
            ++off;
        }
    }
    __syncthreads();

    // distances: registers for k < PCAP, global spill beyond
    int m2 = min(n, PCAP);
    int lv[16];
#pragma unroll
    for (int t = 0; t < 16; ++t) {
        int k = tid + t * 1024;
        lv[t] = INT_MAX;   // sentinel (> BIGI): excluded from max, never <= search pivot
        if (k < m2) { int e = qb[k]; lv[t] = nearest2(sS, e >> 8, e & 255); }
    }
    for (int k = PCAP + tid; k < n; k += 1024) {
        int e = spillq[(size_t)pd * HWP + k - PCAP];
        spillv[(size_t)pd * HWP + k - PCAP] = nearest2(sS, e >> 8, e & 255);
    }
    __syncthreads();   // spillv visible block-wide (same CU); also qb reads done

    // block max
    int lmax = -1;
#pragma unroll
    for (int t = 0; t < 16; ++t) if (lv[t] != INT_MAX) lmax = max(lmax, lv[t]);
    for (int k = PCAP + tid; k < n; k += 1024) lmax = max(lmax, spillv[(size_t)pd * HWP + k - PCAP]);
    for (int off = 32; off; off >>= 1) lmax = max(lmax, __shfl_down(lmax, off));
    if (lane == 0) sw[wid] = lmax;
    __syncthreads();
    if (tid == 0) { int v = -1; for (int w = 0; w < 16; ++w) v = max(v, sw[w]); stot = v; }
    __syncthreads();
    int vmax = stot;
    __syncthreads();

    if (n == 0) {
        if (tid == 0) { res[pd * 2 + 0] = INFINITY; res[pd * 2 + 1] = INFINITY; }
        return;
    }
    // replicate jnp: idx = clip(ceil(f32(0.95)*f32(n)) - 1, 0, ...); k = idx+1
    int kk;
    { float kf = ceilf(0.95f * (float)n); kk = (int)kf; if (kk < 1) kk = 1; if (kk > n) kk = n; }
    // binary search: smallest v in [0, min(vmax,72962)] with count(<=v) >= kk
    int lo = 0, hi = min(vmax, 72962);
    while (lo < hi) {
        int mid = (lo + hi) >> 1;
        int cc = 0;
#pragma unroll
        for (int t = 0; t < 16; ++t) if (lv[t] <= mid) cc++;
        for (int k = PCAP + tid; k < n; k += 1024) if (spillv[(size_t)pd * HWP + k - PCAP] <= mid) cc++;
        for (int off = 32; off; off >>= 1) cc += __shfl_down(cc, off);
        if (lane == 0) sw[wid] = cc;
        __syncthreads();
        if (tid == 0) { int s = 0; for (int w = 0; w < 16; ++w) s += sw[w]; stot = s; }
        __syncthreads();
        if (stot >= kk) hi = mid; else lo = mid + 1;
        __syncthreads();
    }
    int cc = 0;
#pragma unroll
    for (int t = 0; t < 16; ++t) if (lv[t] <= lo) cc++;
    for (int k = PCAP + tid; k < n; k += 1024) if (spillv[(size_t)pd * HWP + k - PCAP] <= lo) cc++;
    for (int off = 32; off; off >>= 1) cc += __shfl_down(cc, off);
    if (lane == 0) sw[wid] = cc;
    __syncthreads();
    if (tid == 0) {
        int s = 0; for (int w = 0; w < 16; ++w) s += sw[w];
        int v95 = (s >= kk) ? lo : BIGI;   // not enough reals -> BIGI (all-BIG case)
        res[pd * 2 + 0] = sqrtf((float)vmax);
        res[pd * 2 + 1] = sqrtf((float)v95);
    }
}

// ---- kernel 3: robust max across directions, mean over pairs (one wave) -----
__global__ void k_final(const float* __restrict__ res, float* __restrict__ out) {
    int tid = threadIdx.x;
    float v100 = 0.0f, v95 = 0.0f;
    if (tid < NPAIR) {
        v100 = fmaxf(res[tid * 4 + 0], res[tid * 4 + 2]);
        v95  = fmaxf(res[tid * 4 + 1], res[tid * 4 + 3]);
    }
    for (int off = 32; off; off >>= 1) {
        v100 += __shfl_down(v100, off);
        v95  += __shfl_down(v95, off);
    }
    if (tid == 0) {
        out[0] = v100 / (float)NPAIR;
        out[1] = v95 / (float)NPAIR;
    }
}

extern "C" void kernel_launch(void* const* d_in, const int* in_sizes, int n_in,
                              void* d_out, int out_size, void* d_ws, size_t ws_size,
                              hipStream_t stream) {
    const float* logits = (const float*)d_in[0];
    const int* target = (const int*)d_in[1];
    float* out = (float*)d_out;

    uint8_t* ws = (uint8_t*)d_ws;
    u64*      fgbits = (u64*)ws;                  // 48*576*8 = 221184 B
    uint16_t* spillq = (uint16_t*)(ws + 221184);  // 48*HWP*2 = 3538944 B (cold)
    int*      spillv = (int*)(ws + 3760128);      // 48*HWP*4 = 7077888 B (cold)
    float*    res    = (float*)(ws + 10838016);   // 96 floats

    k_prep<<<(BB * HWP) / 256, 256, 0, stream>>>(logits, target, fgbits);
    k_main<<<NPD, 1024, 0, stream>>>(fgbits, spillq, spillv, res);
    k_final<<<1, 64, 0, stream>>>(res, out);
}

// Round 10
// 75.503 us; speedup vs baseline: 3.8289x; 1.1923x over previous
//
#include <hip/hip_runtime.h>
#include <hip/hip_bf16.h>
#include <math.h>
#include <stdint.h>
#include <limits.h>

#define BB 8
#define NC 4
#define HH 192
#define WW 192
#define HWP (HH * WW)
#define NPAIR 24            // B * (NC-1)
#define NPD 48              // NPAIR * 2 fields
#define NWRD 576            // HH rows * 3 u64 words per field (= words per image)
#define NCHUNK 16
#define WPC (NWRD / NCHUNK) // 36 words per chunk
#define NBIN 4096           // in-hist d^2 range [0, 4095]; beyond -> overflow list
#define BIGI 1000000000     // matches reference BIG = 1e9 (exact in int32 and f32)

typedef unsigned long long u64;

// ---- kernel 1: argmax + bit-packed fg masks; also zero ghist/ovf ------------
// wave = 64 consecutive pixels -> __ballot builds one u64 mask word directly.
// grid: 1152 x 256 (= B*HWP threads)
__global__ void k_prep(const float* __restrict__ logits, const int* __restrict__ target,
                       u64* __restrict__ fgbits, unsigned* __restrict__ ghist,
                       int* __restrict__ ovfcnt, int* __restrict__ ovfmax) {
    int idx = blockIdx.x * 256 + threadIdx.x;
    if (idx < NPD * NBIN) ghist[idx] = 0;
    if (blockIdx.x == 1151) {
        if (threadIdx.x < NPD) ovfcnt[threadIdx.x] = 0;
        else if (threadIdx.x >= 64 && threadIdx.x < 64 + NPD) ovfmax[threadIdx.x - 64] = 0;
    }
    int b = idx / HWP;
    int p = idx - b * HWP;
    const float* base = logits + (size_t)b * NC * HWP + p;
    float l0 = base[0], l1 = base[HWP], l2 = base[2 * HWP], l3 = base[3 * HWP];
    int pred = 0; float best = l0;
    if (l1 > best) { best = l1; pred = 1; }   // strict > keeps first max (jnp.argmax)
    if (l2 > best) { best = l2; pred = 2; }
    if (l3 > best) { best = l3; pred = 3; }
    int t = target[(size_t)b * HWP + p];
    int lane = threadIdx.x & 63;
    int g = p >> 6;   // word index within field; bit = col&63 (word = i*3 + (j>>6))
#pragma unroll
    for (int cls = 1; cls <= 3; ++cls) {
        u64 mp = __ballot(pred == cls);
        u64 mt = __ballot(t == cls);
        if (lane == 0) {
            int pair = b * 3 + (cls - 1);
            fgbits[(size_t)(pair * 2 + 0) * NWRD + g] = mp;
            fgbits[(size_t)(pair * 2 + 1) * NWRD + g] = mt;
        }
    }
}

// surface word (row i, word k) from fg bitmap F (borders = background)
__device__ __forceinline__ u64 surf_word(const u64* F, int i, int k) {
    u64 r0 = F[i * 3], r1 = F[i * 3 + 1], r2 = F[i * 3 + 2];
    u64 r = F[i * 3 + k];
    u64 u = (i > 0) ? F[(i - 1) * 3 + k] : 0ull;
    u64 d = (i < HH - 1) ? F[(i + 1) * 3 + k] : 0ull;
    u64 lf, rt;
    if (k == 0)      { lf = r0 << 1;                rt = (r0 >> 1) | (r1 << 63); }
    else if (k == 1) { lf = (r1 << 1) | (r0 >> 63); rt = (r1 >> 1) | (r2 << 63); }
    else             { lf = (r2 << 1) | (r1 >> 63); rt = r2 >> 1; }
    return r & ~(u & d & lf & rt);
}

// nearest set-bit horizontal distance to column j in 192-bit row; INT_MAX if empty
__device__ __forceinline__ int rowdist(const u64* w, int j) {
    int qw = j >> 6, qb2 = j & 63;
    int dr = INT_MAX, dl = INT_MAX;
    u64 m = w[qw] & (~0ull << qb2);
    if (m) dr = ((qw << 6) + __ffsll(m) - 1) - j;
    else {
        for (int k = qw + 1; k < 3; ++k)
            if (w[k]) { dr = ((k << 6) + __ffsll(w[k]) - 1) - j; break; }
    }
    u64 ml = w[qw] & (~0ull >> (63 - qb2));
    if (ml) dl = j - ((qw << 6) + 63 - __clzll((long long)ml));
    else {
        for (int k = qw - 1; k >= 0; --k)
            if (w[k]) { dl = j - ((k << 6) + 63 - __clzll((long long)w[k])); break; }
    }
    return min(dl, dr);
}

// ---- kernel 2: surfaces + exact 2D nearest search -> per-pd global hist -----
// Block (chunk, pd): field = surface of pd; queries = surface pixels of pd^1 in
// word slice [chunk*WPC, ...). Empty field -> BIGI exactly (reference BIG path).
// d^2 < 4096 -> LDS hist (merged to ghist); else exact overflow list + max.
// grid: (NCHUNK, NPD), block: 256
__global__ __launch_bounds__(256) void k_query(const u64* __restrict__ fgbits,
                        unsigned* __restrict__ ghist, int* __restrict__ ovfval,
                        int* __restrict__ ovfcnt, int* __restrict__ ovfmax) {
    int chunk = blockIdx.x, pd = blockIdx.y, qpd = pd ^ 1;
    int tid = threadIdx.x;
    __shared__ u64 sF[NWRD];               // fg of pd
    __shared__ u64 sG[NWRD];               // fg of pd^1
    __shared__ u64 sS[NWRD];               // surface of pd (field searched)
    __shared__ uint16_t qb[WPC * 64];      // queries of this chunk (<=2304)
    __shared__ unsigned shist[NBIN];       // 16 KB
    __shared__ int wcnt[WPC + 1];

    for (int t = tid; t < NWRD; t += 256) {
        sF[t] = fgbits[(size_t)pd * NWRD + t];
        sG[t] = fgbits[(size_t)qpd * NWRD + t];
    }
    for (int t = tid; t < NBIN; t += 256) shist[t] = 0;
    __syncthreads();
    for (int w = tid; w < NWRD; w += 256) sS[w] = surf_word(sF, w / 3, w % 3);

    u64 myq = 0;
    if (tid < WPC) {
        int w = chunk * WPC + tid;
        myq = surf_word(sG, w / 3, w % 3);
        wcnt[tid] = __popcll(myq);
    }
    __syncthreads();
    if (tid == 0) {
        int acc = 0;
        for (int w = 0; w < WPC; ++w) { int c = wcnt[w]; wcnt[w] = acc; acc += c; }
        wcnt[WPC] = acc;
    }
    __syncthreads();
    if (tid < WPC) {
        int w = chunk * WPC + tid;
        int i = w / 3, k = w % 3;
        int off = wcnt[tid];
        u64 m = myq;
        while (m) { int bi = __ffsll(m) - 1; m &= m - 1; qb[off++] = (uint16_t)((i << 8) | (k * 64 + bi)); }
    }
    __syncthreads();

    int nq = wcnt[WPC];
    for (int q = tid; q < nq; q += 256) {
        int e = qb[q];
        int qi = e >> 8, qj = e & 255;
        int best = BIGI;
        for (int s = 0; s < HH; ++s) {
            if (s * s >= best) break;                      // exact prune
            int r = qi - s;
            if (r >= 0) {
                int dj = rowdist(sS + r * 3, qj);
                if (dj != INT_MAX) best = min(best, s * s + dj * dj);
            }
            r = qi + s;
            if (s > 0 && r < HH) {
                int dj = rowdist(sS + r * 3, qj);
                if (dj != INT_MAX) best = min(best, s * s + dj * dj);
            }
        }
        if (best < NBIN) {
            atomicAdd(&shist[best], 1u);
        } else {                                           // exact overflow path
            int ix = atomicAdd(&ovfcnt[pd], 1);
            ovfval[(size_t)pd * HWP + ix] = best;
            atomicMax(&ovfmax[pd], best);
        }
    }
    __syncthreads();
    for (int bin = tid; bin < NBIN; bin += 256)
        if (shist[bin]) atomicAdd(&ghist[pd * NBIN + bin], shist[bin]);
}

// ---- kernel 3: per-pd percentile from histogram -----------------------------
// grid: NPD, block: 256 (4 waves). Each thread owns 16 consecutive bins.
__global__ __launch_bounds__(256) void k_sel(const unsigned* __restrict__ ghist,
                        const int* __restrict__ ovfval, const int* __restrict__ ovfcnt,
                        const int* __restrict__ ovfmax, float* __restrict__ res) {
    int pd = blockIdx.x, tid = threadIdx.x, lane = tid & 63, wid = tid >> 6;
    __shared__ int swt[4];
    __shared__ int sred[4];
    __shared__ int sv95;
    const unsigned* H = ghist + pd * NBIN;

    unsigned c[16];
    int s_t = 0;
#pragma unroll
    for (int u = 0; u < 16; ++u) { c[u] = H[tid * 16 + u]; s_t += (int)c[u]; }

    // block exclusive scan of per-thread sums
    int inc = s_t;
    for (int off = 1; off < 64; off <<= 1) { int t = __shfl_up(inc, off); if (lane >= off) inc += t; }
    if (lane == 63) swt[wid] = inc;
    __syncthreads();
    int woff = 0;
    for (int w = 0; w < wid; ++w) woff += swt[w];
    int total = swt[0] + swt[1] + swt[2] + swt[3];
    int base = woff + inc - s_t;   // exclusive prefix of this thread

    int novf = ovfcnt[pd];
    int n = total + novf;

    // vmax: highest nonzero bin, or overflow max
    int mybin = -1;
#pragma unroll
    for (int u = 0; u < 16; ++u) if (c[u]) mybin = tid * 16 + u;
    for (int off = 32; off; off >>= 1) mybin = max(mybin, __shfl_down(mybin, off));
    if (lane == 0) sred[wid] = mybin;
    __syncthreads();
    int vmax = max(max(sred[0], sred[1]), max(sred[2], sred[3]));
    if (novf > 0) vmax = max(vmax, ovfmax[pd]);

    if (n == 0) {
        if (tid == 0) { res[pd * 2 + 0] = INFINITY; res[pd * 2 + 1] = INFINITY; }
        return;
    }
    // replicate jnp: idx = clip(ceil(f32(0.95)*f32(n)) - 1, 0, ...); k = idx+1
    int kk;
    { float kf = ceilf(0.95f * (float)n); kk = (int)kf; if (kk < 1) kk = 1; if (kk > n) kk = n; }

    if (kk <= total) {
        // the unique thread whose bin-chunk spans rank kk scans serially
        if (base < kk && kk <= base + s_t) {
            int cum = base;
#pragma unroll
            for (int u = 0; u < 16; ++u) {
                cum += (int)c[u];
                if (cum >= kk) { sv95 = tid * 16 + u; break; }
            }
        }
        __syncthreads();
        if (tid == 0) {
            res[pd * 2 + 0] = sqrtf((float)vmax);
            res[pd * 2 + 1] = sqrtf((float)sv95);
        }
    } else {
        // rank falls in overflow values (cold path; exact binary search on value)
        int r = kk - total;
        const int* OV = ovfval + (size_t)pd * HWP;
        int lo = NBIN, hi = vmax;
        while (lo < hi) {
            int mid = lo + ((hi - lo) >> 1);
            int cc = 0;
            for (int k = tid; k < novf; k += 256) if (OV[k] <= mid) cc++;
            for (int off = 32; off; off >>= 1) cc += __shfl_down(cc, off);
            if (lane == 0) sred[wid] = cc;
            __syncthreads();
            int tot = sred[0] + sred[1] + sred[2] + sred[3];
            __syncthreads();
            if (tot >= r) hi = mid; else lo = mid + 1;
        }
        if (tid == 0) {
            res[pd * 2 + 0] = sqrtf((float)vmax);
            res[pd * 2 + 1] = sqrtf((float)lo);
        }
    }
}

// ---- kernel 4: robust max across directions, mean over pairs (one wave) -----
__global__ void k_final(const float* __restrict__ res, float* __restrict__ out) {
    int tid = threadIdx.x;
    float v100 = 0.0f, v95 = 0.0f;
    if (tid < NPAIR) {
        v100 = fmaxf(res[tid * 4 + 0], res[tid * 4 + 2]);
        v95  = fmaxf(res[tid * 4 + 1], res[tid * 4 + 3]);
    }
    for (int off = 32; off; off >>= 1) {
        v100 += __shfl_down(v100, off);
        v95  += __shfl_down(v95, off);
    }
    if (tid == 0) {
        out[0] = v100 / (float)NPAIR;
        out[1] = v95 / (float)NPAIR;
    }
}

extern "C" void kernel_launch(void* const* d_in, const int* in_sizes, int n_in,
                              void* d_out, int out_size, void* d_ws, size_t ws_size,
                              hipStream_t stream) {
    const float* logits = (const float*)d_in[0];
    const int* target = (const int*)d_in[1];
    float* out = (float*)d_out;

    uint8_t* ws = (uint8_t*)d_ws;
    u64*      fgbits = (u64*)ws;                  // 221184 B
    unsigned* ghist  = (unsigned*)(ws + 221184);  // 48*4096*4 = 786432 B
    int*      ovfval = (int*)(ws + 1007616);      // 48*HWP*4 = 7077888 B (cold)
    int*      ovfcnt = (int*)(ws + 8085504);      // 48 ints
    int*      ovfmax = (int*)(ws + 8085696);      // 48 ints
    float*    res    = (float*)(ws + 8085888);    // 96 floats

    k_prep<<<(BB * HWP) / 256, 256, 0, stream>>>(logits, target, fgbits, ghist, ovfcnt, ovfmax);
    k_query<<<dim3(NCHUNK, NPD), 256, 0, stream>>>(fgbits, ghist, ovfval, ovfcnt, ovfmax);
    k_sel<<<NPD, 256, 0, stream>>>(ghist, ovfval, ovfcnt, ovfmax, res);
    k_final<<<1, 64, 0, stream>>>(res, out);
}